// Round 13
// baseline (17184.233 us; speedup 1.0000x reference)
//
#include <hip/hip_runtime.h>
#include <hip/hip_bf16.h>

// BiLSTM-CRF on MI355X.  VOCAB=50000, EMB=256, HID=512 (H=256/dir), NTAG=20, SEQ=8192.
//
// Round-13: r4's proven exchange (sentinel poll on out[], agent scope) with
// r8's leaner compute core, minus r8's regressions:
//  * gate-interleaved lanes: act->cell via 3 shfl_down, no gates_lds, 2
//    barriers/step instead of 3 (per-row arithmetic order unchanged ->
//    bit-identical h to r4/r12).
//  * single publish store (no priv array, no asm ring).
//  * poller waves 4-6 start the dependent-load poll right after B1
//    (overlaps act/cell/publish); echo pollers waves 7-9 poll the same
//    words phase-offset by s_sleep(4) (~256cy) -> expected discovery
//    penalty halves. Both write identical values to h_lds.
// Scan floor analysis: fp32 weights (1MB/dir) need >= 4 CUs' RFs; the
// one exchange RT/step (~2300cy) is structural. This round removes the
// ~400cy of non-RT overhead.

#define S    8192
#define E    256
#define Hh   256          // per-direction hidden
#define G    1024         // 4*Hh gates
#define NT   20
#define NB   4            // blocks (CUs) per direction
#define NCHUNK 128        // 8192 / 64
#define CLEN   64
#define SENT 0x7FC0DEADu  // NaN bit pattern; h values are never NaN

// ---------------------------------------------------------------- sentinel fill
__global__ __launch_bounds__(256) void sentinel_fill(unsigned int* __restrict__ lo_u)
{
    size_t base = (size_t)blockIdx.x * 1024 + threadIdx.x;
    #pragma unroll
    for (int i = 0; i < 4; ++i)
        __hip_atomic_store(&lo_u[base + (size_t)i * 256], SENT,
                           __ATOMIC_RELAXED, __HIP_MEMORY_SCOPE_AGENT);
}

// ---------------------------------------------------------------- xg projection
__global__ __launch_bounds__(1024, 4) void xg_project(
    const int* __restrict__ sent, const float* __restrict__ embed,
    const float* __restrict__ Wih_f, const float* __restrict__ bih_f, const float* __restrict__ bhh_f,
    const float* __restrict__ Wih_b, const float* __restrict__ bih_b, const float* __restrict__ bhh_b,
    float* __restrict__ xg)                       // [2][S][G]
{
    const int tb  = blockIdx.x;                   // 0..255 (32 timesteps each)
    const int rb  = blockIdx.y;                   // 0..3
    const int dir = blockIdx.z;                   // 0..1
    const int tid = threadIdx.x;
    const int q   = tid >> 8;                     // k-quarter 0..3
    const int idx = tid & 255;
    const int r   = rb * 256 + idx;               // gate row 0..1023
    const float* Wih = dir ? Wih_b : Wih_f;

    __shared__ __align__(16) float4 xs4[32 * 64]; // 32 timesteps x 256 floats (32 KB)
    __shared__ float psum[1024];

    const int t0 = tb * 32;
    #pragma unroll
    for (int i = 0; i < 2; ++i) {
        int qq  = i * 1024 + tid;                 // 2048 float4 total
        int row = qq >> 6;
        int c4  = qq & 63;
        int widx = sent[t0 + row];
        xs4[qq] = *(const float4*)(embed + (size_t)widx * E + (size_t)c4 * 4);
    }

    float w[64];
    #pragma unroll
    for (int k = 0; k < 64; k += 4) {
        float4 v = *(const float4*)(Wih + (size_t)r * E + q * 64 + k);
        w[k] = v.x; w[k+1] = v.y; w[k+2] = v.z; w[k+3] = v.w;
    }
    float bias = 0.f;
    if (tid < 256) bias = dir ? (bih_b[r] + bhh_b[r]) : (bih_f[r] + bhh_f[r]);
    __syncthreads();

    const float* xs = (const float*)xs4 + q * 64;
    float* outb = xg + ((size_t)dir * S + t0) * G + r;
    for (int tt = 0; tt < 32; ++tt) {
        float a0 = 0.f, a1 = 0.f, a2 = 0.f, a3 = 0.f;
        #pragma unroll
        for (int k = 0; k < 64; k += 4) {
            float4 h4 = *(const float4*)(xs + tt * E + k);   // LDS broadcast
            a0 = fmaf(w[k],   h4.x, a0);
            a1 = fmaf(w[k+1], h4.y, a1);
            a2 = fmaf(w[k+2], h4.z, a2);
            a3 = fmaf(w[k+3], h4.w, a3);
        }
        psum[tid] = (a0 + a1) + (a2 + a3);
        __syncthreads();
        if (tid < 256)
            outb[(size_t)tt * G] = bias +
                ((psum[idx] + psum[idx + 256]) + (psum[idx + 512] + psum[idx + 768]));
        __syncthreads();                          // psum reused next tt
    }
}

// ---------------------------------------------------------------- LSTM scan
// Grid (NB,2). Block (b,dir) owns h [b*64,b*64+64) = 256 gate rows.
// Thread (q=tid>>8, idx=tid&255): gate=idx&3, hloc=idx>>2,
// row = gate*256 + b*64 + hloc (gate-interleaved), k-range q*64..q*64+64.
// Waves 4-6: pollers; waves 7-9: echo pollers (s_sleep phase offset).
__global__ __launch_bounds__(1024, 4) void lstm_scan_gi(
    const float* __restrict__ xg,                 // [2][S][G]
    const float* __restrict__ Whh_f,
    const float* __restrict__ Whh_b,
    float* __restrict__ out)                      // [S][512], sentinel-prefilled
{
    const int b    = blockIdx.x;
    const int dir  = blockIdx.y;
    const int tid  = threadIdx.x;
    const int q    = tid >> 8;
    const int idx  = tid & 255;
    const int gate = idx & 3;
    const int hloc = idx >> 2;
    const int hidx = b * 64 + hloc;
    const int row  = gate * Hh + hidx;
    const float* W   = dir ? Whh_b : Whh_f;
    const float* xgd = xg + (size_t)dir * S * G;

    float w[64];
    #pragma unroll
    for (int k = 0; k < 64; k += 4) {
        float4 v = *(const float4*)(W + (size_t)row * Hh + q * 64 + k);
        w[k] = v.x; w[k+1] = v.y; w[k+2] = v.z; w[k+3] = v.w;
    }

    __shared__ __align__(16) float h_lds[Hh];
    __shared__ float psum[1024];
    if (tid < Hh) h_lds[tid] = 0.f;
    float c = 0.f;

    // poller roles
    const bool isPoll = (tid >= 256 && tid < 448);   // waves 4-6
    const bool isEcho = (tid >= 448 && tid < 640);   // waves 7-9
    const int  pl     = isPoll ? (tid - 256) : (isEcho ? (tid - 448) : 0);
    const int  pi     = pl >> 6;                     // 0..2 (wave-uniform)
    const int  word   = pl & 63;
    const int  pb     = pi + (pi >= b);              // peer block id

    const int t0 = dir ? (S - 1) : 0;
    const int dt = dir ? -1 : 1;
    float xg_cur = (tid < 256) ? xgd[(size_t)t0 * G + row] : 0.f;
    __syncthreads();

    for (int s = 0; s < S; ++s) {
        const int t = t0 + dt * s;
        float xg_next = 0.f;
        if (tid < 256 && s + 1 < S) xg_next = xgd[(size_t)(t + dt) * G + row];

        // partial matvec over this thread's k-quarter (wave-uniform LDS bcast)
        const float* hh = (const float*)h_lds + q * 64;
        float a0 = 0.f, a1 = 0.f, a2 = 0.f, a3 = 0.f;
        #pragma unroll
        for (int k = 0; k < 64; k += 4) {
            float4 h4 = *(const float4*)(hh + k);
            a0 = fmaf(w[k],   h4.x, a0);
            a1 = fmaf(w[k+1], h4.y, a1);
            a2 = fmaf(w[k+2], h4.z, a2);
            a3 = fmaf(w[k+3], h4.w, a3);
        }
        psum[tid] = (a0 + a1) + (a2 + a3);
        __syncthreads();                                     // B1: partials ready

        if (tid < 256) {
            // combine + activation (same arithmetic order as r4/r12 per row)
            float acc = xg_cur +
                ((psum[idx] + psum[idx + 256]) + (psum[idx + 512] + psum[idx + 768]));
            float a = (gate == 2) ? tanhf(acc) : 1.f / (1.f + expf(-acc));
            float fv = __shfl_down(a, 1);
            float gv = __shfl_down(a, 2);
            float ov = __shfl_down(a, 3);
            if (gate == 0) {                                 // cell lane (i-gate)
                c = fv * c + a * gv;
                float h = ov * tanhf(c);
                __hip_atomic_store(out + (size_t)t * 512 + dir * Hh + hidx, h,
                                   __ATOMIC_RELAXED, __HIP_MEMORY_SCOPE_AGENT);
                h_lds[hidx] = h;                             // own segment direct
            }
        } else if (isPoll && s + 1 < S) {
            // poll peer pb's word (starts at B1, overlaps act/cell/publish)
            const unsigned int* srcp =
                (const unsigned int*)(out + (size_t)t * 512 + dir * Hh + pb * 64 + word);
            unsigned int v;
            do {
                v = __hip_atomic_load(srcp, __ATOMIC_RELAXED,
                                      __HIP_MEMORY_SCOPE_AGENT);
            } while (v == SENT);
            h_lds[pb * 64 + word] = __uint_as_float(v);
        } else if (isEcho && s + 1 < S) {
            // phase-offset echo poll of the same word (same value write)
            __builtin_amdgcn_s_sleep(4);                     // ~256cy offset
            const unsigned int* srcp =
                (const unsigned int*)(out + (size_t)t * 512 + dir * Hh + pb * 64 + word);
            unsigned int v;
            do {
                v = __hip_atomic_load(srcp, __ATOMIC_RELAXED,
                                      __HIP_MEMORY_SCOPE_AGENT);
            } while (v == SENT);
            h_lds[pb * 64 + word] = __uint_as_float(v);
        }
        __syncthreads();                                     // B2: h(t) in LDS
        xg_cur = xg_next;
    }
}

// ---------------------------------------------------------------- emissions
__global__ __launch_bounds__(256) void emissions_kernel(
    const float* __restrict__ lo,                 // [S][512]
    const float* __restrict__ Wout,               // [NT][512]
    const float* __restrict__ bout,
    float* __restrict__ em)                       // [S][NT]
{
    int gid = blockIdx.x * blockDim.x + threadIdx.x;
    if (gid >= S * NT) return;
    int t = gid / NT;
    int j = gid - t * NT;
    const float* x = lo + (size_t)t * 512;
    const float* w = Wout + (size_t)j * 512;
    float a0 = 0.f, a1 = 0.f, a2 = 0.f, a3 = 0.f;
    #pragma unroll 8
    for (int k = 0; k < 512; k += 4) {
        float4 xv = *(const float4*)(x + k);
        float4 wv = *(const float4*)(w + k);
        a0 = fmaf(xv.x, wv.x, a0);
        a1 = fmaf(xv.y, wv.y, a1);
        a2 = fmaf(xv.z, wv.z, a2);
        a3 = fmaf(xv.w, wv.w, a3);
    }
    em[gid] = bout[j] + ((a0 + a1) + (a2 + a3));
}

// ---------------------------------------------------------------- viterbi forward
// Single wave, no barriers. Lane j (<20) owns score j. Per iteration:
// ds_write snew -> 5 uniform ds_read_b128 (same-wave LDS ops are ordered) ->
// 20 adds -> 19-combine argmax tree (index-ordered strict > == first-index).
__device__ __forceinline__ void vit_cmb(float& va, int& ia, float vb, int ib) {
    if (vb > va) { va = vb; ia = ib; }
}

__global__ __launch_bounds__(64) void viterbi_fwd(
    const float* __restrict__ em,                 // [S][NT]
    const float* __restrict__ start_trans,
    const float* __restrict__ end_trans,
    const float* __restrict__ trans,              // [NT][NT] (from,to)
    unsigned char* __restrict__ bp,               // [S][NT]
    int* __restrict__ last_out)
{
    const int lane = threadIdx.x;
    const bool act = (lane < NT);
    const int j = act ? lane : 0;                 // spectators mirror lane 0

    __shared__ __align__(16) float sc[24];        // score vector (single wave)

    float tc[NT];                                 // trans column j
    #pragma unroll
    for (int i = 0; i < NT; ++i) tc[i] = trans[i * NT + j];

    float snew = start_trans[j] + em[j];          // score(0), lane-local
    if (act) bp[lane] = (unsigned char)lane;      // t=0: identity (never used)
    float e0 = em[NT + j];                        // em(1)
    float e1 = em[2 * NT + j];                    // em(2)

    for (int t = 1; t < S; ++t) {
        if (act) sc[lane] = snew;                 // ds_write
        __builtin_amdgcn_wave_barrier();          // keep LDS op order (free)
        float s0[NT];
        #pragma unroll
        for (int i = 0; i < NT; i += 4) {         // 5 uniform b128 reads
            float4 v = *(const float4*)(sc + i);
            s0[i] = v.x; s0[i+1] = v.y; s0[i+2] = v.z; s0[i+3] = v.w;
        }
        __builtin_amdgcn_wave_barrier();          // reads before next write

        float e2 = (t + 2 < S) ? em[(size_t)(t + 2) * NT + j] : 0.f;

        float cv[NT];
        #pragma unroll
        for (int i = 0; i < NT; ++i) cv[i] = s0[i] + tc[i];

        // argmax tree (first-index ties)
        float v1[10]; int i1[10];
        #pragma unroll
        for (int u = 0; u < 10; ++u) {
            v1[u] = cv[2*u]; i1[u] = 2*u;
            vit_cmb(v1[u], i1[u], cv[2*u+1], 2*u+1);
        }
        float v2[5]; int i2[5];
        #pragma unroll
        for (int u = 0; u < 5; ++u) {
            v2[u] = v1[2*u]; i2[u] = i1[2*u];
            vit_cmb(v2[u], i2[u], v1[2*u+1], i1[2*u+1]);
        }
        float v3a = v2[0]; int i3a = i2[0];
        vit_cmb(v3a, i3a, v2[1], i2[1]);
        float v3b = v2[2]; int i3b = i2[2];
        vit_cmb(v3b, i3b, v2[3], i2[3]);
        vit_cmb(v3a, i3a, v3b, i3b);              // covers 0..15
        vit_cmb(v3a, i3a, v2[4], i2[4]);          // 16..19 last (index order)

        snew = v3a + e0;
        if (act) bp[(size_t)t * NT + lane] = (unsigned char)i3a;
        e0 = e1; e1 = e2;
    }

    if (act) sc[lane] = snew + end_trans[j];
    __builtin_amdgcn_wave_barrier();
    {
        float s0[NT];
        #pragma unroll
        for (int i = 0; i < NT; i += 4) {
            float4 v = *(const float4*)(sc + i);
            s0[i] = v.x; s0[i+1] = v.y; s0[i+2] = v.z; s0[i+3] = v.w;
        }
        float bv = s0[0]; int bi = 0;
        #pragma unroll
        for (int i = 1; i < NT; ++i) vit_cmb(bv, bi, s0[i], i);
        if (lane == 0) *last_out = bi;
    }
}

// ---------------------------------------------------------------- backtrace
__global__ __launch_bounds__(64) void bt_maps(
    const unsigned char* __restrict__ bp, unsigned char* __restrict__ maps)
{
    __shared__ unsigned char lbp[CLEN * NT];
    const int c = blockIdx.x, tid = threadIdx.x;
    const unsigned* src = (const unsigned*)(bp + (size_t)c * CLEN * NT);
    unsigned* dst = (unsigned*)lbp;
    for (int q = tid; q < CLEN * NT / 4; q += 64) dst[q] = src[q];
    __syncthreads();
    if (tid < NT) {
        int x = tid;
        for (int t = CLEN - 1; t >= 0; --t) x = lbp[t * NT + x];
        maps[c * NT + tid] = (unsigned char)x;
    }
}

__global__ __launch_bounds__(64) void bt_boundary(
    const unsigned char* __restrict__ maps, const int* __restrict__ last_out,
    int* __restrict__ btags)
{
    __shared__ unsigned char m[NCHUNK * NT];
    const int tid = threadIdx.x;
    for (int q = tid; q < NCHUNK * NT; q += 64) m[q] = maps[q];
    __syncthreads();
    if (tid == 0) {
        int x = *last_out;
        btags[NCHUNK - 1] = x;
        for (int c = NCHUNK - 1; c >= 1; --c) {
            x = m[c * NT + x];
            btags[c - 1] = x;
        }
    }
}

__global__ __launch_bounds__(64) void bt_emit(
    const unsigned char* __restrict__ bp, const int* __restrict__ btags,
    int* __restrict__ path)
{
    __shared__ unsigned char lbp[CLEN * NT];
    const int c = blockIdx.x, tid = threadIdx.x;
    const unsigned* src = (const unsigned*)(bp + (size_t)c * CLEN * NT);
    unsigned* dst = (unsigned*)lbp;
    for (int q = tid; q < CLEN * NT / 4; q += 64) dst[q] = src[q];
    __syncthreads();
    if (tid == 0) {
        int x = btags[c];
        path[c * CLEN + CLEN - 1] = x;
        for (int t = CLEN - 1; t >= 1; --t) {
            x = lbp[t * NT + x];
            path[c * CLEN + t - 1] = x;
        }
    }
}

// ---------------------------------------------------------------- launcher
extern "C" void kernel_launch(void* const* d_in, const int* in_sizes, int n_in,
                              void* d_out, int out_size, void* d_ws, size_t ws_size,
                              hipStream_t stream) {
    const int*   sent   = (const int*)  d_in[0];
    const float* embed  = (const float*)d_in[1];
    const float* Wih_f  = (const float*)d_in[2];
    const float* Whh_f  = (const float*)d_in[3];
    const float* bih_f  = (const float*)d_in[4];
    const float* bhh_f  = (const float*)d_in[5];
    const float* Wih_b  = (const float*)d_in[6];
    const float* Whh_b  = (const float*)d_in[7];
    const float* bih_b  = (const float*)d_in[8];
    const float* bhh_b  = (const float*)d_in[9];
    const float* Wout   = (const float*)d_in[10];
    const float* bout   = (const float*)d_in[11];
    const float* start_trans = (const float*)d_in[12];
    const float* end_trans   = (const float*)d_in[13];
    const float* trans       = (const float*)d_in[14];
    int* path = (int*)d_out;

    char* ws = (char*)d_ws;
    size_t off = 0;
    float* xg = (float*)(ws + off); off += (size_t)2 * S * G * 4;   // 64 MB
    float* lo = (float*)(ws + off); off += (size_t)S * 512 * 4;     // 16 MB
    float* em = (float*)(ws + off); off += (size_t)S * NT * 4;      // 640 KB
    unsigned char* bp   = (unsigned char*)(ws + off); off += (size_t)S * NT;  // 160 KB
    unsigned char* maps = (unsigned char*)(ws + off); off += 4096;
    int* btags = (int*)(ws + off); off += 1024;
    int* lastp = (int*)(ws + off); off += 256;

    sentinel_fill<<<dim3(4096), 256, 0, stream>>>((unsigned int*)lo);
    xg_project<<<dim3(S / 32, 4, 2), 1024, 0, stream>>>(
        sent, embed, Wih_f, bih_f, bhh_f, Wih_b, bih_b, bhh_b, xg);
    lstm_scan_gi<<<dim3(NB, 2), 1024, 0, stream>>>(xg, Whh_f, Whh_b, lo);
    emissions_kernel<<<dim3((S * NT + 255) / 256), 256, 0, stream>>>(lo, Wout, bout, em);
    viterbi_fwd<<<dim3(1), 64, 0, stream>>>(em, start_trans, end_trans, trans, bp, lastp);
    bt_maps<<<dim3(NCHUNK), 64, 0, stream>>>(bp, maps);
    bt_boundary<<<dim3(1), 64, 0, stream>>>(maps, lastp, btags);
    bt_emit<<<dim3(NCHUNK), 64, 0, stream>>>(bp, btags, path);
}